// Round 1
// baseline (1583.980 us; speedup 1.0000x reference)
//
#include <hip/hip_runtime.h>

#define NPn 100000
#define NSn 50000
#define PDk 1024
#define SDk 512
#define EPe 3200000
#define ESe 1600000
#define ELe 2000000
#define NB_P 196   // ceil(100000/512)
#define NB_S 98    // ceil(50000/512)
#define CHUNK 8192

// ---- bucket histogram: bcnt[b] += #edges with dst>>9 == b ----
__global__ void k_bhist(const int* __restrict__ dst, int E, int* __restrict__ bcnt,
                        int NB) {
  __shared__ int h[256];
  int t = threadIdx.x;
  if (t < NB) h[t] = 0;
  __syncthreads();
  for (int i = blockIdx.x * 256 + t; i < E; i += gridDim.x * 256)
    atomicAdd(&h[dst[i] >> 9], 1);
  __syncthreads();
  if (t < NB && h[t]) atomicAdd(&bcnt[t], h[t]);
}

// ---- tiny scan over buckets (<=256), one block of 256 threads ----
__global__ void k_bscan(const int* __restrict__ bcnt, int* __restrict__ boff,
                        int* __restrict__ bcur, int NB, int E, int* __restrict__ row,
                        int N) {
  __shared__ int wsum[4];
  int t = threadIdx.x, lane = t & 63, w = t >> 6;
  int v = (t < NB) ? bcnt[t] : 0;
  int x = v;
#pragma unroll
  for (int off = 1; off < 64; off <<= 1) {
    int y = __shfl_up(x, off);
    if (lane >= off) x += y;
  }
  if (lane == 63) wsum[w] = x;
  __syncthreads();
  int woff = 0;
  for (int j = 0; j < w; ++j) woff += wsum[j];
  int ex = woff + x - v;
  if (t < NB) { boff[t] = ex; bcur[t] = ex; }
  if (t == 0) { boff[NB] = E; row[N] = E; }
}

// ---- blocked partition: per-block LDS hist -> one global reserve per bucket ->
//      LDS staging grouped by bucket -> coalesced windowed writes ----
__global__ __launch_bounds__(256) void k_bucket2(const int* __restrict__ src,
                                                 const int* __restrict__ dst, int E,
                                                 int* __restrict__ bcur,
                                                 int* __restrict__ bdata, int NB) {
  __shared__ int hist[256];
  __shared__ int lofs[256];
  __shared__ int delta[256];
  __shared__ int lcur[256];
  __shared__ int wsum[4];
  __shared__ int stage[CHUNK];
  int t = threadIdx.x;
  int base = blockIdx.x * CHUNK;
  int cnt = min(CHUNK, E - base);
  hist[t] = 0;
  __syncthreads();
  for (int i = t; i < cnt; i += 256) atomicAdd(&hist[dst[base + i] >> 9], 1);
  __syncthreads();
  // exclusive scan of hist[0..255]
  int v = hist[t];
  int lane = t & 63, w = t >> 6;
  int x = v;
#pragma unroll
  for (int off = 1; off < 64; off <<= 1) {
    int y = __shfl_up(x, off);
    if (lane >= off) x += y;
  }
  if (lane == 63) wsum[w] = x;
  __syncthreads();
  int woff = 0;
  for (int j = 0; j < w; ++j) woff += wsum[j];
  int ex = woff + x - v;
  lofs[t] = ex;
  lcur[t] = ex;
  if (t < NB) delta[t] = atomicAdd(&bcur[t], v) - ex;  // global window base - local base
  __syncthreads();
  // local placement into stage, grouped by bucket
  for (int i = t; i < cnt; i += 256) {
    int d = dst[base + i];
    int b = d >> 9;
    int p = atomicAdd(&lcur[b], 1);
    stage[p] = (src[base + i] << 9) | (d & 511);
  }
  __syncthreads();
  // stream out: consecutive slots -> consecutive global addrs within a segment
  for (int i = t; i < cnt; i += 256) {
    int lo = 0, hi = NB;  // largest b with lofs[b] <= i
    while (hi - lo > 1) {
      int mid = (lo + hi) >> 1;
      if (lofs[mid] <= i) lo = mid; else hi = mid;
    }
    bdata[delta[lo] + i] = stage[i];
  }
}

// ---- per-bucket: local hist -> scan -> row/dinv/col ----
__global__ __launch_bounds__(256) void k_build(const int* __restrict__ bdata,
                                               const int* __restrict__ boff,
                                               int* __restrict__ col,
                                               int* __restrict__ row,
                                               float* __restrict__ dinv, int N) {
  __shared__ int hist[512];
  __shared__ int excl[512];
  __shared__ int wsum[4];
  int b = blockIdx.x, t = threadIdx.x;
  int s = boff[b], e = boff[b + 1];
  int n0 = b << 9;
  hist[t] = 0; hist[t + 256] = 0;
  __syncthreads();
  for (int i = s + t; i < e; i += 256) atomicAdd(&hist[bdata[i] & 511], 1);
  __syncthreads();
  int a0 = hist[2 * t], a1 = hist[2 * t + 1];
  int ps = a0 + a1;
  int lane = t & 63, w = t >> 6;
  int x = ps;
#pragma unroll
  for (int off = 1; off < 64; off <<= 1) {
    int y = __shfl_up(x, off);
    if (lane >= off) x += y;
  }
  if (lane == 63) wsum[w] = x;
  __syncthreads();
  int woff = 0;
  for (int j = 0; j < w; ++j) woff += wsum[j];
  int ex = woff + x - ps;
  excl[2 * t] = ex;
  excl[2 * t + 1] = ex + a0;
  __syncthreads();
  for (int l = t; l < 512; l += 256) {
    int n = n0 + l;
    if (n < N) {
      row[n] = s + excl[l];
      dinv[n] = rsqrtf((float)(hist[l] + 1));
    }
  }
  __syncthreads();
  for (int i = s + t; i < e; i += 256) {
    int v = bdata[i];
    int p = atomicAdd(&excl[v & 511], 1);
    col[s + p] = v >> 9;
  }
}

// C[M,64] = A[M,K] @ W[K,64], K % 32 == 0. 256 thr, 128x64 tile, 8x4 micro.
// FMA:LDS-issue per thread per k-step = 1024:112 (vs 512:72 at 64x64/4x4).
__global__ __launch_bounds__(256) void k_gemm128(const float* __restrict__ A,
                                                 const float* __restrict__ W,
                                                 float* __restrict__ C, int M, int K) {
  __shared__ float as[32][132];  // k-major (transposed) A tile, pad 132 (132%32=4)
  __shared__ float bs[32][68];
  int tid = threadIdx.x;
  int tx = tid & 15;   // 16 col-groups of 4
  int ty = tid >> 4;   // 16 row-groups of 8
  int row0 = blockIdx.x * 128;
  float acc[8][4] = {};
  for (int k0 = 0; k0 < K; k0 += 32) {
    {
      // A tile: 128 rows x 32 k. 2 threads/row, 16 consecutive floats each.
      int r = tid >> 1;
      int kk = (tid & 1) * 16;
      int grow = row0 + r;
      float4 v0 = make_float4(0.f, 0.f, 0.f, 0.f), v1 = v0, v2 = v0, v3 = v0;
      if (grow < M) {
        const float* srcp = A + (size_t)grow * K + k0 + kk;
        v0 = ((const float4*)srcp)[0];
        v1 = ((const float4*)srcp)[1];
        v2 = ((const float4*)srcp)[2];
        v3 = ((const float4*)srcp)[3];
      }
      as[kk + 0][r] = v0.x;  as[kk + 1][r] = v0.y;  as[kk + 2][r] = v0.z;  as[kk + 3][r] = v0.w;
      as[kk + 4][r] = v1.x;  as[kk + 5][r] = v1.y;  as[kk + 6][r] = v1.z;  as[kk + 7][r] = v1.w;
      as[kk + 8][r] = v2.x;  as[kk + 9][r] = v2.y;  as[kk + 10][r] = v2.z; as[kk + 11][r] = v2.w;
      as[kk + 12][r] = v3.x; as[kk + 13][r] = v3.y; as[kk + 14][r] = v3.z; as[kk + 15][r] = v3.w;
    }
    {
      int kk = tid >> 3;
      int n = (tid & 7) * 8;
      const float* srcp = W + (size_t)(k0 + kk) * 64 + n;
      float4 v0 = *(const float4*)(srcp);
      float4 v1 = *(const float4*)(srcp + 4);
      *(float4*)&bs[kk][n] = v0;
      *(float4*)&bs[kk][n + 4] = v1;
    }
    __syncthreads();
#pragma unroll
    for (int kk = 0; kk < 32; ++kk) {
      float4 a0 = *(const float4*)&as[kk][ty * 8];
      float4 a1 = *(const float4*)&as[kk][ty * 8 + 4];
      float4 b = *(const float4*)&bs[kk][tx * 4];
      float av[8] = {a0.x, a0.y, a0.z, a0.w, a1.x, a1.y, a1.z, a1.w};
      float bv[4] = {b.x, b.y, b.z, b.w};
#pragma unroll
      for (int i = 0; i < 8; ++i)
#pragma unroll
        for (int j = 0; j < 4; ++j) acc[i][j] += av[i] * bv[j];
    }
    __syncthreads();
  }
  int r0 = row0 + ty * 8, c0 = tx * 4;
#pragma unroll
  for (int i = 0; i < 8; ++i) {
    int r = r0 + i;
    if (r < M)
      *(float4*)&C[(size_t)r * 64 + c0] =
          make_float4(acc[i][0], acc[i][1], acc[i][2], acc[i][3]);
  }
}

// out[i,:] = dinv[i]*( sum_j dinv[j]*h[j,:] + dinv[i]*h[i,:] ) + bias
__global__ void k_agg(const float* __restrict__ h, const int* __restrict__ row,
                      const int* __restrict__ col, const float* __restrict__ dinv,
                      const float* __restrict__ bias, float* __restrict__ out, int N) {
  int w = threadIdx.x >> 6, lane = threadIdx.x & 63;
  int i = blockIdx.x * 4 + w;
  if (i >= N) return;
  float di = dinv[i];
  int s = row[i], e = row[i + 1];
  float acc0 = di * h[(size_t)i * 64 + lane];
  float acc1 = 0.f, acc2 = 0.f, acc3 = 0.f;
  for (int base = s; base < e; base += 64) {
    int idx = base + lane;
    int cidx = (idx < e) ? col[idx] : 0;
    float dv = (idx < e) ? dinv[cidx] : 0.f;
    int cnt = min(64, e - base);
    int t = 0;
    for (; t + 4 <= cnt; t += 4) {
      int j0 = __shfl(cidx, t), j1 = __shfl(cidx, t + 1);
      int j2 = __shfl(cidx, t + 2), j3 = __shfl(cidx, t + 3);
      float d0 = __shfl(dv, t), d1 = __shfl(dv, t + 1);
      float d2 = __shfl(dv, t + 2), d3 = __shfl(dv, t + 3);
      float h0 = h[(size_t)j0 * 64 + lane];
      float h1v = h[(size_t)j1 * 64 + lane];
      float h2 = h[(size_t)j2 * 64 + lane];
      float h3 = h[(size_t)j3 * 64 + lane];
      acc0 += d0 * h0; acc1 += d1 * h1v; acc2 += d2 * h2; acc3 += d3 * h3;
    }
    for (; t < cnt; ++t) {
      int j = __shfl(cidx, t);
      float dj = __shfl(dv, t);
      acc0 += dj * h[(size_t)j * 64 + lane];
    }
  }
  out[(size_t)i * 64 + lane] = di * (acc0 + acc1 + acc2 + acc3) + bias[lane];
}

// fold: M = Wproj[sel]@Wl1 (64x64); W2m = W2@M; c2 = b2@M; cvec = bproj@Wl1 + bl1
__global__ __launch_bounds__(1024) void k_fold2(
    const float* __restrict__ Wproj, const float* __restrict__ bproj,
    const float* __restrict__ Wl1, const float* __restrict__ bl1,
    const float* __restrict__ Wp2, const float* __restrict__ bp2,
    const float* __restrict__ Ws2, const float* __restrict__ bs2,
    float* __restrict__ W2m_p, float* __restrict__ c2_p, float* __restrict__ W2m_s,
    float* __restrict__ c2_s, float* __restrict__ cvec) {
  int which = blockIdx.x;
  const float* W2 = which ? Ws2 : Wp2;
  const float* b2v = which ? bs2 : bp2;
  float* W2m = which ? W2m_s : W2m_p;
  float* c2 = which ? c2_s : c2_p;
  __shared__ float M[64][64];
  int t = threadIdx.x;
  for (int idx = t; idx < 4096; idx += 1024) {
    int a = idx >> 6, c = idx & 63;
    const float* wr = Wproj + (size_t)(which * 64 + a) * 128;
    float sum = 0.f;
    for (int k = 0; k < 128; ++k) sum += wr[k] * Wl1[(size_t)k * 64 + c];
    M[a][c] = sum;
  }
  __syncthreads();
  for (int idx = t; idx < 4096; idx += 1024) {
    int a = idx >> 6, c = idx & 63;
    float sum = 0.f;
    for (int k = 0; k < 64; ++k) sum += W2[a * 64 + k] * M[k][c];
    W2m[idx] = sum;
  }
  if (t < 64) {
    float sum = 0.f;
    for (int k = 0; k < 64; ++k) sum += b2v[k] * M[k][t];
    c2[t] = sum;
  }
  if (which == 0 && t >= 64 && t < 128) {
    int c = t - 64;
    float sum = bl1[c];
    for (int k = 0; k < 128; ++k) sum += bproj[k] * Wl1[(size_t)k * 64 + c];
    cvec[c] = sum;
  }
}

// out[e] = relu(P[ep[e],:] + S[es[e],:] + c) . wl2 + bl2   (16 lanes per edge)
__global__ void k_link(const float* __restrict__ P, const float* __restrict__ S,
                       const int* __restrict__ ep, const int* __restrict__ es,
                       const float* __restrict__ cvec, const float* __restrict__ wl2,
                       const float* __restrict__ bl2, float* __restrict__ out, int EL) {
  int lane = threadIdx.x & 63;
  int g = lane >> 4;
  int f = lane & 15;
  int wave = threadIdx.x >> 6;
  float4 c4 = *(const float4*)&cvec[f * 4];
  float4 w4 = *(const float4*)&wl2[f * 4];
  float b2 = bl2[0];
  int e0 = blockIdx.x * 16 + wave * 4 + g;
  int step = gridDim.x * 16;
  for (int e = e0; e < EL; e += step) {
    int rp = ep[e], rs = es[e];
    float4 p4 = *(const float4*)&P[(size_t)rp * 64 + f * 4];
    float4 s4 = *(const float4*)&S[(size_t)rs * 64 + f * 4];
    float u, acc;
    u = p4.x + s4.x + c4.x; acc  = fmaxf(u, 0.f) * w4.x;
    u = p4.y + s4.y + c4.y; acc += fmaxf(u, 0.f) * w4.y;
    u = p4.z + s4.z + c4.z; acc += fmaxf(u, 0.f) * w4.z;
    u = p4.w + s4.w + c4.w; acc += fmaxf(u, 0.f) * w4.w;
    acc += __shfl_xor(acc, 1);
    acc += __shfl_xor(acc, 2);
    acc += __shfl_xor(acc, 4);
    acc += __shfl_xor(acc, 8);
    if (f == 0) out[e] = acc + b2;
  }
}

extern "C" void kernel_launch(void* const* d_in, const int* in_sizes, int n_in,
                              void* d_out, int out_size, void* d_ws, size_t ws_size,
                              hipStream_t stream) {
  const float* x_p  = (const float*)d_in[0];
  const float* x_s  = (const float*)d_in[1];
  const int*   ei_p = (const int*)d_in[2];
  const int*   ei_s = (const int*)d_in[3];
  const int*   ed_p = (const int*)d_in[4];
  const int*   ed_s = (const int*)d_in[5];
  const float* Wp1 = (const float*)d_in[6];  const float* bp1 = (const float*)d_in[7];
  const float* Ws1 = (const float*)d_in[8];  const float* bs1 = (const float*)d_in[9];
  const float* Wp2 = (const float*)d_in[10]; const float* bp2 = (const float*)d_in[11];
  const float* Ws2 = (const float*)d_in[12]; const float* bs2 = (const float*)d_in[13];
  const float* Wproj = (const float*)d_in[14]; const float* bproj = (const float*)d_in[15];
  const float* Wl1 = (const float*)d_in[16]; const float* bl1 = (const float*)d_in[17];
  const float* Wl2 = (const float*)d_in[18]; const float* bl2 = (const float*)d_in[19];
  float* out = (float*)d_out;

  char* wsp = (char*)d_ws;
  size_t off = 0;
  auto alloc = [&](size_t b) -> void* {
    void* p = wsp + off;
    off = (off + b + 255) & ~(size_t)255;
    return p;
  };
  float* bufA_p = (float*)alloc((size_t)NPn * 64 * 4);
  float* bufB_p = (float*)alloc((size_t)NPn * 64 * 4);
  float* bufA_s = (float*)alloc((size_t)NSn * 64 * 4);
  float* bufB_s = (float*)alloc((size_t)NSn * 64 * 4);
  int*   col_p  = (int*)alloc((size_t)EPe * 4);
  int*   col_s  = (int*)alloc((size_t)ESe * 4);
  float* dinv_p = (float*)alloc((size_t)NPn * 4);
  float* dinv_s = (float*)alloc((size_t)NSn * 4);
  int*   row_p  = (int*)alloc((size_t)(NPn + 1) * 4);
  int*   row_s  = (int*)alloc((size_t)(NSn + 1) * 4);
  int*   bcnt_p = (int*)alloc(256 * 4);
  int*   bcnt_s = (int*)alloc(256 * 4);
  int*   boff_p = (int*)alloc(257 * 4);
  int*   boff_s = (int*)alloc(257 * 4);
  int*   bcur_p = (int*)alloc(256 * 4);
  int*   bcur_s = (int*)alloc(256 * 4);
  float* W2m_p  = (float*)alloc(64 * 64 * 4);
  float* W2m_s  = (float*)alloc(64 * 64 * 4);
  float* c2_p   = (float*)alloc(64 * 4);
  float* c2_s   = (float*)alloc(64 * 4);
  float* cvec   = (float*)alloc(64 * 4);
  (void)ws_size; (void)n_in; (void)in_sizes; (void)out_size;

  // bdata aliases bufA (only used before the GEMMs touch bufA; stream is serial)
  int* bdata_p = (int*)bufA_p;
  int* bdata_s = (int*)bufA_s;

  const int* src_p = ei_p;           const int* dst_p = ei_p + EPe;
  const int* src_s = ei_s;           const int* dst_s = ei_s + ESe;

  hipMemsetAsync(bcnt_p, 0, 256 * 4, stream);
  hipMemsetAsync(bcnt_s, 0, 256 * 4, stream);

  // weight folding (independent)
  k_fold2<<<2, 1024, 0, stream>>>(Wproj, bproj, Wl1, bl1, Wp2, bp2, Ws2, bs2,
                                  W2m_p, c2_p, W2m_s, c2_s, cvec);

  // bucket counting-sort CSR build
  k_bhist<<<1280, 256, 0, stream>>>(dst_p, EPe, bcnt_p, NB_P);
  k_bhist<<<1280, 256, 0, stream>>>(dst_s, ESe, bcnt_s, NB_S);
  k_bscan<<<1, 256, 0, stream>>>(bcnt_p, boff_p, bcur_p, NB_P, EPe, row_p, NPn);
  k_bscan<<<1, 256, 0, stream>>>(bcnt_s, boff_s, bcur_s, NB_S, ESe, row_s, NSn);
  k_bucket2<<<(EPe + CHUNK - 1) / CHUNK, 256, 0, stream>>>(src_p, dst_p, EPe, bcur_p,
                                                           bdata_p, NB_P);
  k_bucket2<<<(ESe + CHUNK - 1) / CHUNK, 256, 0, stream>>>(src_s, dst_s, ESe, bcur_s,
                                                           bdata_s, NB_S);
  k_build<<<NB_P, 256, 0, stream>>>(bdata_p, boff_p, col_p, row_p, dinv_p, NPn);
  k_build<<<NB_S, 256, 0, stream>>>(bdata_s, boff_s, col_s, row_s, dinv_s, NSn);

  // protein: t = x@W1 ; h1 = Agg(t)+b1 ; t = h1@W2m ; P = Agg(t)+c2
  k_gemm128<<<(NPn + 127) / 128, 256, 0, stream>>>(x_p, Wp1, bufA_p, NPn, PDk);
  k_agg<<<(NPn + 3) / 4, 256, 0, stream>>>(bufA_p, row_p, col_p, dinv_p, bp1, bufB_p, NPn);
  k_gemm128<<<(NPn + 127) / 128, 256, 0, stream>>>(bufB_p, W2m_p, bufA_p, NPn, 64);
  k_agg<<<(NPn + 3) / 4, 256, 0, stream>>>(bufA_p, row_p, col_p, dinv_p, c2_p, bufB_p, NPn);

  // substrate
  k_gemm128<<<(NSn + 127) / 128, 256, 0, stream>>>(x_s, Ws1, bufA_s, NSn, SDk);
  k_agg<<<(NSn + 3) / 4, 256, 0, stream>>>(bufA_s, row_s, col_s, dinv_s, bs1, bufB_s, NSn);
  k_gemm128<<<(NSn + 127) / 128, 256, 0, stream>>>(bufB_s, W2m_s, bufA_s, NSn, 64);
  k_agg<<<(NSn + 3) / 4, 256, 0, stream>>>(bufA_s, row_s, col_s, dinv_s, c2_s, bufB_s, NSn);

  // link predictor
  k_link<<<(ELe + 15) / 16, 256, 0, stream>>>(bufB_p, bufB_s, ed_p, ed_s, cvec, Wl2,
                                              bl2, out, ELe);
}

// Round 2
// 1582.782 us; speedup vs baseline: 1.0008x; 1.0008x over previous
//
#include <hip/hip_runtime.h>

#define NPn 100000
#define NSn 50000
#define PDk 1024
#define SDk 512
#define EPe 3200000
#define ESe 1600000
#define ELe 2000000
#define NB_P 196   // ceil(100000/512)
#define NB_S 98    // ceil(50000/512)
#define CHUNK 8192

// ---- bucket histogram: bcnt[b] += #edges with dst>>9 == b ----
__global__ void k_bhist(const int* __restrict__ dst, int E, int* __restrict__ bcnt,
                        int NB) {
  __shared__ int h[256];
  int t = threadIdx.x;
  if (t < NB) h[t] = 0;
  __syncthreads();
  for (int i = blockIdx.x * 256 + t; i < E; i += gridDim.x * 256)
    atomicAdd(&h[dst[i] >> 9], 1);
  __syncthreads();
  if (t < NB && h[t]) atomicAdd(&bcnt[t], h[t]);
}

// ---- tiny scan over buckets (<=256), one block of 256 threads ----
__global__ void k_bscan(const int* __restrict__ bcnt, int* __restrict__ boff,
                        int* __restrict__ bcur, int NB, int E, int* __restrict__ row,
                        int N) {
  __shared__ int wsum[4];
  int t = threadIdx.x, lane = t & 63, w = t >> 6;
  int v = (t < NB) ? bcnt[t] : 0;
  int x = v;
#pragma unroll
  for (int off = 1; off < 64; off <<= 1) {
    int y = __shfl_up(x, off);
    if (lane >= off) x += y;
  }
  if (lane == 63) wsum[w] = x;
  __syncthreads();
  int woff = 0;
  for (int j = 0; j < w; ++j) woff += wsum[j];
  int ex = woff + x - v;
  if (t < NB) { boff[t] = ex; bcur[t] = ex; }
  if (t == 0) { boff[NB] = E; row[N] = E; }
}

// ---- blocked partition: per-block LDS hist -> one global reserve per bucket ->
//      LDS staging grouped by bucket -> coalesced windowed writes ----
__global__ __launch_bounds__(256) void k_bucket2(const int* __restrict__ src,
                                                 const int* __restrict__ dst, int E,
                                                 int* __restrict__ bcur,
                                                 int* __restrict__ bdata, int NB) {
  __shared__ int hist[256];
  __shared__ int lofs[256];
  __shared__ int delta[256];
  __shared__ int lcur[256];
  __shared__ int wsum[4];
  __shared__ int stage[CHUNK];
  int t = threadIdx.x;
  int base = blockIdx.x * CHUNK;
  int cnt = min(CHUNK, E - base);
  hist[t] = 0;
  __syncthreads();
  for (int i = t; i < cnt; i += 256) atomicAdd(&hist[dst[base + i] >> 9], 1);
  __syncthreads();
  // exclusive scan of hist[0..255]
  int v = hist[t];
  int lane = t & 63, w = t >> 6;
  int x = v;
#pragma unroll
  for (int off = 1; off < 64; off <<= 1) {
    int y = __shfl_up(x, off);
    if (lane >= off) x += y;
  }
  if (lane == 63) wsum[w] = x;
  __syncthreads();
  int woff = 0;
  for (int j = 0; j < w; ++j) woff += wsum[j];
  int ex = woff + x - v;
  lofs[t] = ex;
  lcur[t] = ex;
  if (t < NB) delta[t] = atomicAdd(&bcur[t], v) - ex;  // global window base - local base
  __syncthreads();
  // local placement into stage, grouped by bucket
  for (int i = t; i < cnt; i += 256) {
    int d = dst[base + i];
    int b = d >> 9;
    int p = atomicAdd(&lcur[b], 1);
    stage[p] = (src[base + i] << 9) | (d & 511);
  }
  __syncthreads();
  // stream out: consecutive slots -> consecutive global addrs within a segment
  for (int i = t; i < cnt; i += 256) {
    int lo = 0, hi = NB;  // largest b with lofs[b] <= i
    while (hi - lo > 1) {
      int mid = (lo + hi) >> 1;
      if (lofs[mid] <= i) lo = mid; else hi = mid;
    }
    bdata[delta[lo] + i] = stage[i];
  }
}

// ---- per-bucket: local hist -> scan -> row/dinv/col ----
__global__ __launch_bounds__(256) void k_build(const int* __restrict__ bdata,
                                               const int* __restrict__ boff,
                                               int* __restrict__ col,
                                               int* __restrict__ row,
                                               float* __restrict__ dinv, int N) {
  __shared__ int hist[512];
  __shared__ int excl[512];
  __shared__ int wsum[4];
  int b = blockIdx.x, t = threadIdx.x;
  int s = boff[b], e = boff[b + 1];
  int n0 = b << 9;
  hist[t] = 0; hist[t + 256] = 0;
  __syncthreads();
  for (int i = s + t; i < e; i += 256) atomicAdd(&hist[bdata[i] & 511], 1);
  __syncthreads();
  int a0 = hist[2 * t], a1 = hist[2 * t + 1];
  int ps = a0 + a1;
  int lane = t & 63, w = t >> 6;
  int x = ps;
#pragma unroll
  for (int off = 1; off < 64; off <<= 1) {
    int y = __shfl_up(x, off);
    if (lane >= off) x += y;
  }
  if (lane == 63) wsum[w] = x;
  __syncthreads();
  int woff = 0;
  for (int j = 0; j < w; ++j) woff += wsum[j];
  int ex = woff + x - ps;
  excl[2 * t] = ex;
  excl[2 * t + 1] = ex + a0;
  __syncthreads();
  for (int l = t; l < 512; l += 256) {
    int n = n0 + l;
    if (n < N) {
      row[n] = s + excl[l];
      dinv[n] = rsqrtf((float)(hist[l] + 1));
    }
  }
  __syncthreads();
  for (int i = s + t; i < e; i += 256) {
    int v = bdata[i];
    int p = atomicAdd(&excl[v & 511], 1);
    col[s + p] = v >> 9;
  }
}

// C[M,64] = A[M,K] @ W[K,64], K % 32 == 0. 256 thr, 128x64 tile, 8x4 micro.
__global__ __launch_bounds__(256) void k_gemm128(const float* __restrict__ A,
                                                 const float* __restrict__ W,
                                                 float* __restrict__ C, int M, int K) {
  __shared__ float as[32][132];  // k-major (transposed) A tile, pad 132 (132%32=4)
  __shared__ float bs[32][68];
  int tid = threadIdx.x;
  int tx = tid & 15;   // 16 col-groups of 4
  int ty = tid >> 4;   // 16 row-groups of 8
  int row0 = blockIdx.x * 128;
  float acc[8][4] = {};
  for (int k0 = 0; k0 < K; k0 += 32) {
    {
      // A tile: 128 rows x 32 k. 2 threads/row, 16 consecutive floats each.
      int r = tid >> 1;
      int kk = (tid & 1) * 16;
      int grow = row0 + r;
      float4 v0 = make_float4(0.f, 0.f, 0.f, 0.f), v1 = v0, v2 = v0, v3 = v0;
      if (grow < M) {
        const float* srcp = A + (size_t)grow * K + k0 + kk;
        v0 = ((const float4*)srcp)[0];
        v1 = ((const float4*)srcp)[1];
        v2 = ((const float4*)srcp)[2];
        v3 = ((const float4*)srcp)[3];
      }
      as[kk + 0][r] = v0.x;  as[kk + 1][r] = v0.y;  as[kk + 2][r] = v0.z;  as[kk + 3][r] = v0.w;
      as[kk + 4][r] = v1.x;  as[kk + 5][r] = v1.y;  as[kk + 6][r] = v1.z;  as[kk + 7][r] = v1.w;
      as[kk + 8][r] = v2.x;  as[kk + 9][r] = v2.y;  as[kk + 10][r] = v2.z; as[kk + 11][r] = v2.w;
      as[kk + 12][r] = v3.x; as[kk + 13][r] = v3.y; as[kk + 14][r] = v3.z; as[kk + 15][r] = v3.w;
    }
    {
      int kk = tid >> 3;
      int n = (tid & 7) * 8;
      const float* srcp = W + (size_t)(k0 + kk) * 64 + n;
      float4 v0 = *(const float4*)(srcp);
      float4 v1 = *(const float4*)(srcp + 4);
      *(float4*)&bs[kk][n] = v0;
      *(float4*)&bs[kk][n + 4] = v1;
    }
    __syncthreads();
#pragma unroll
    for (int kk = 0; kk < 32; ++kk) {
      float4 a0 = *(const float4*)&as[kk][ty * 8];
      float4 a1 = *(const float4*)&as[kk][ty * 8 + 4];
      float4 b = *(const float4*)&bs[kk][tx * 4];
      float av[8] = {a0.x, a0.y, a0.z, a0.w, a1.x, a1.y, a1.z, a1.w};
      float bv[4] = {b.x, b.y, b.z, b.w};
#pragma unroll
      for (int i = 0; i < 8; ++i)
#pragma unroll
        for (int j = 0; j < 4; ++j) acc[i][j] += av[i] * bv[j];
    }
    __syncthreads();
  }
  int r0 = row0 + ty * 8, c0 = tx * 4;
#pragma unroll
  for (int i = 0; i < 8; ++i) {
    int r = r0 + i;
    if (r < M)
      *(float4*)&C[(size_t)r * 64 + c0] =
          make_float4(acc[i][0], acc[i][1], acc[i][2], acc[i][3]);
  }
}

// out[i,:] = dinv[i]*( sum_j dinv[j]*h[j,:] + dinv[i]*h[i,:] ) + bias
// Wave = 1 node. 4 edge-groups of 16 lanes; each group gathers a float4 slice
// of a different neighbor row -> 1024 B per vector-memory issue (4x fewer
// requests and 4x fewer shuffles per edge than dword/lane layout).
__global__ __launch_bounds__(256) void k_agg(const float* __restrict__ h,
                                             const int* __restrict__ row,
                                             const int* __restrict__ col,
                                             const float* __restrict__ dinv,
                                             const float* __restrict__ bias,
                                             float* __restrict__ out, int N) {
  int w = threadIdx.x >> 6, lane = threadIdx.x & 63;
  int g = lane >> 4;   // edge-group 0..3
  int f = lane & 15;   // feature quad: features [4f, 4f+4)
  int i = blockIdx.x * 4 + w;
  if (i >= N) return;
  float di = dinv[i];
  int s = row[i], e = row[i + 1];
  float4 acc = make_float4(0.f, 0.f, 0.f, 0.f);
  if (g == 0) {  // self-loop term, counted once
    float4 hv = *(const float4*)&h[(size_t)i * 64 + f * 4];
    acc.x = di * hv.x; acc.y = di * hv.y; acc.z = di * hv.z; acc.w = di * hv.w;
  }
  for (int base = s; base < e; base += 64) {
    int idx = base + lane;
    int cidx = (idx < e) ? col[idx] : 0;
    float dv = (idx < e) ? dinv[cidx] : 0.f;  // 0-weight padding for tail
    int cnt = min(64, e - base);
    int nt = (cnt + 3) >> 2;
    for (int t = 0; t < nt; ++t) {
      int sl = t * 4 + g;
      int j = __shfl(cidx, sl);
      float dj = __shfl(dv, sl);
      float4 hv = *(const float4*)&h[(size_t)j * 64 + f * 4];
      acc.x += dj * hv.x; acc.y += dj * hv.y; acc.z += dj * hv.z; acc.w += dj * hv.w;
    }
  }
  // fold the 4 edge-groups (feature layout is identical across groups)
  acc.x += __shfl_xor(acc.x, 16); acc.y += __shfl_xor(acc.y, 16);
  acc.z += __shfl_xor(acc.z, 16); acc.w += __shfl_xor(acc.w, 16);
  acc.x += __shfl_xor(acc.x, 32); acc.y += __shfl_xor(acc.y, 32);
  acc.z += __shfl_xor(acc.z, 32); acc.w += __shfl_xor(acc.w, 32);
  if (lane < 16) {
    float4 b4 = *(const float4*)&bias[f * 4];
    float4 o;
    o.x = di * acc.x + b4.x; o.y = di * acc.y + b4.y;
    o.z = di * acc.z + b4.z; o.w = di * acc.w + b4.w;
    *(float4*)&out[(size_t)i * 64 + f * 4] = o;
  }
}

// fold: M = Wproj[sel]@Wl1 (64x64); W2m = W2@M; c2 = b2@M; cvec = bproj@Wl1 + bl1
__global__ __launch_bounds__(1024) void k_fold2(
    const float* __restrict__ Wproj, const float* __restrict__ bproj,
    const float* __restrict__ Wl1, const float* __restrict__ bl1,
    const float* __restrict__ Wp2, const float* __restrict__ bp2,
    const float* __restrict__ Ws2, const float* __restrict__ bs2,
    float* __restrict__ W2m_p, float* __restrict__ c2_p, float* __restrict__ W2m_s,
    float* __restrict__ c2_s, float* __restrict__ cvec) {
  int which = blockIdx.x;
  const float* W2 = which ? Ws2 : Wp2;
  const float* b2v = which ? bs2 : bp2;
  float* W2m = which ? W2m_s : W2m_p;
  float* c2 = which ? c2_s : c2_p;
  __shared__ float M[64][64];
  int t = threadIdx.x;
  for (int idx = t; idx < 4096; idx += 1024) {
    int a = idx >> 6, c = idx & 63;
    const float* wr = Wproj + (size_t)(which * 64 + a) * 128;
    float sum = 0.f;
    for (int k = 0; k < 128; ++k) sum += wr[k] * Wl1[(size_t)k * 64 + c];
    M[a][c] = sum;
  }
  __syncthreads();
  for (int idx = t; idx < 4096; idx += 1024) {
    int a = idx >> 6, c = idx & 63;
    float sum = 0.f;
    for (int k = 0; k < 64; ++k) sum += W2[a * 64 + k] * M[k][c];
    W2m[idx] = sum;
  }
  if (t < 64) {
    float sum = 0.f;
    for (int k = 0; k < 64; ++k) sum += b2v[k] * M[k][t];
    c2[t] = sum;
  }
  if (which == 0 && t >= 64 && t < 128) {
    int c = t - 64;
    float sum = bl1[c];
    for (int k = 0; k < 128; ++k) sum += bproj[k] * Wl1[(size_t)k * 64 + c];
    cvec[c] = sum;
  }
}

// out[e] = relu(P[ep[e],:] + S[es[e],:] + c) . wl2 + bl2   (16 lanes per edge)
__global__ void k_link(const float* __restrict__ P, const float* __restrict__ S,
                       const int* __restrict__ ep, const int* __restrict__ es,
                       const float* __restrict__ cvec, const float* __restrict__ wl2,
                       const float* __restrict__ bl2, float* __restrict__ out, int EL) {
  int lane = threadIdx.x & 63;
  int g = lane >> 4;
  int f = lane & 15;
  int wave = threadIdx.x >> 6;
  float4 c4 = *(const float4*)&cvec[f * 4];
  float4 w4 = *(const float4*)&wl2[f * 4];
  float b2 = bl2[0];
  int e0 = blockIdx.x * 16 + wave * 4 + g;
  int step = gridDim.x * 16;
  for (int e = e0; e < EL; e += step) {
    int rp = ep[e], rs = es[e];
    float4 p4 = *(const float4*)&P[(size_t)rp * 64 + f * 4];
    float4 s4 = *(const float4*)&S[(size_t)rs * 64 + f * 4];
    float u, acc;
    u = p4.x + s4.x + c4.x; acc  = fmaxf(u, 0.f) * w4.x;
    u = p4.y + s4.y + c4.y; acc += fmaxf(u, 0.f) * w4.y;
    u = p4.z + s4.z + c4.z; acc += fmaxf(u, 0.f) * w4.z;
    u = p4.w + s4.w + c4.w; acc += fmaxf(u, 0.f) * w4.w;
    acc += __shfl_xor(acc, 1);
    acc += __shfl_xor(acc, 2);
    acc += __shfl_xor(acc, 4);
    acc += __shfl_xor(acc, 8);
    if (f == 0) out[e] = acc + b2;
  }
}

extern "C" void kernel_launch(void* const* d_in, const int* in_sizes, int n_in,
                              void* d_out, int out_size, void* d_ws, size_t ws_size,
                              hipStream_t stream) {
  const float* x_p  = (const float*)d_in[0];
  const float* x_s  = (const float*)d_in[1];
  const int*   ei_p = (const int*)d_in[2];
  const int*   ei_s = (const int*)d_in[3];
  const int*   ed_p = (const int*)d_in[4];
  const int*   ed_s = (const int*)d_in[5];
  const float* Wp1 = (const float*)d_in[6];  const float* bp1 = (const float*)d_in[7];
  const float* Ws1 = (const float*)d_in[8];  const float* bs1 = (const float*)d_in[9];
  const float* Wp2 = (const float*)d_in[10]; const float* bp2 = (const float*)d_in[11];
  const float* Ws2 = (const float*)d_in[12]; const float* bs2 = (const float*)d_in[13];
  const float* Wproj = (const float*)d_in[14]; const float* bproj = (const float*)d_in[15];
  const float* Wl1 = (const float*)d_in[16]; const float* bl1 = (const float*)d_in[17];
  const float* Wl2 = (const float*)d_in[18]; const float* bl2 = (const float*)d_in[19];
  float* out = (float*)d_out;

  char* wsp = (char*)d_ws;
  size_t off = 0;
  auto alloc = [&](size_t b) -> void* {
    void* p = wsp + off;
    off = (off + b + 255) & ~(size_t)255;
    return p;
  };
  float* bufA_p = (float*)alloc((size_t)NPn * 64 * 4);
  float* bufB_p = (float*)alloc((size_t)NPn * 64 * 4);
  float* bufA_s = (float*)alloc((size_t)NSn * 64 * 4);
  float* bufB_s = (float*)alloc((size_t)NSn * 64 * 4);
  int*   col_p  = (int*)alloc((size_t)EPe * 4);
  int*   col_s  = (int*)alloc((size_t)ESe * 4);
  float* dinv_p = (float*)alloc((size_t)NPn * 4);
  float* dinv_s = (float*)alloc((size_t)NSn * 4);
  int*   row_p  = (int*)alloc((size_t)(NPn + 1) * 4);
  int*   row_s  = (int*)alloc((size_t)(NSn + 1) * 4);
  int*   bcnt_p = (int*)alloc(256 * 4);
  int*   bcnt_s = (int*)alloc(256 * 4);
  int*   boff_p = (int*)alloc(257 * 4);
  int*   boff_s = (int*)alloc(257 * 4);
  int*   bcur_p = (int*)alloc(256 * 4);
  int*   bcur_s = (int*)alloc(256 * 4);
  float* W2m_p  = (float*)alloc(64 * 64 * 4);
  float* W2m_s  = (float*)alloc(64 * 64 * 4);
  float* c2_p   = (float*)alloc(64 * 4);
  float* c2_s   = (float*)alloc(64 * 4);
  float* cvec   = (float*)alloc(64 * 4);
  (void)ws_size; (void)n_in; (void)in_sizes; (void)out_size;

  // bdata aliases bufA (only used before the GEMMs touch bufA; stream is serial)
  int* bdata_p = (int*)bufA_p;
  int* bdata_s = (int*)bufA_s;

  const int* src_p = ei_p;           const int* dst_p = ei_p + EPe;
  const int* src_s = ei_s;           const int* dst_s = ei_s + ESe;

  hipMemsetAsync(bcnt_p, 0, 256 * 4, stream);
  hipMemsetAsync(bcnt_s, 0, 256 * 4, stream);

  // weight folding (independent)
  k_fold2<<<2, 1024, 0, stream>>>(Wproj, bproj, Wl1, bl1, Wp2, bp2, Ws2, bs2,
                                  W2m_p, c2_p, W2m_s, c2_s, cvec);

  // bucket counting-sort CSR build
  k_bhist<<<1280, 256, 0, stream>>>(dst_p, EPe, bcnt_p, NB_P);
  k_bhist<<<1280, 256, 0, stream>>>(dst_s, ESe, bcnt_s, NB_S);
  k_bscan<<<1, 256, 0, stream>>>(bcnt_p, boff_p, bcur_p, NB_P, EPe, row_p, NPn);
  k_bscan<<<1, 256, 0, stream>>>(bcnt_s, boff_s, bcur_s, NB_S, ESe, row_s, NSn);
  k_bucket2<<<(EPe + CHUNK - 1) / CHUNK, 256, 0, stream>>>(src_p, dst_p, EPe, bcur_p,
                                                           bdata_p, NB_P);
  k_bucket2<<<(ESe + CHUNK - 1) / CHUNK, 256, 0, stream>>>(src_s, dst_s, ESe, bcur_s,
                                                           bdata_s, NB_S);
  k_build<<<NB_P, 256, 0, stream>>>(bdata_p, boff_p, col_p, row_p, dinv_p, NPn);
  k_build<<<NB_S, 256, 0, stream>>>(bdata_s, boff_s, col_s, row_s, dinv_s, NSn);

  // protein: t = x@W1 ; h1 = Agg(t)+b1 ; t = h1@W2m ; P = Agg(t)+c2
  k_gemm128<<<(NPn + 127) / 128, 256, 0, stream>>>(x_p, Wp1, bufA_p, NPn, PDk);
  k_agg<<<(NPn + 3) / 4, 256, 0, stream>>>(bufA_p, row_p, col_p, dinv_p, bp1, bufB_p, NPn);
  k_gemm128<<<(NPn + 127) / 128, 256, 0, stream>>>(bufB_p, W2m_p, bufA_p, NPn, 64);
  k_agg<<<(NPn + 3) / 4, 256, 0, stream>>>(bufA_p, row_p, col_p, dinv_p, c2_p, bufB_p, NPn);

  // substrate
  k_gemm128<<<(NSn + 127) / 128, 256, 0, stream>>>(x_s, Ws1, bufA_s, NSn, SDk);
  k_agg<<<(NSn + 3) / 4, 256, 0, stream>>>(bufA_s, row_s, col_s, dinv_s, bs1, bufB_s, NSn);
  k_gemm128<<<(NSn + 127) / 128, 256, 0, stream>>>(bufB_s, W2m_s, bufA_s, NSn, 64);
  k_agg<<<(NSn + 3) / 4, 256, 0, stream>>>(bufA_s, row_s, col_s, dinv_s, c2_s, bufB_s, NSn);

  // link predictor
  k_link<<<(ELe + 15) / 16, 256, 0, stream>>>(bufB_p, bufB_s, ed_p, ed_s, cvec, Wl2,
                                              bl2, out, ELe);
}

// Round 3
// 1402.721 us; speedup vs baseline: 1.1292x; 1.1284x over previous
//
#include <hip/hip_runtime.h>

#define NPn 100000
#define NSn 50000
#define PDk 1024
#define SDk 512
#define EPe 3200000
#define ESe 1600000
#define ELe 2000000
#define NB_P 196   // ceil(100000/512)
#define NB_S 98    // ceil(50000/512)
#define CHUNK 8192

// ---- bf16 helpers: rows are 64 x bf16 = 128 B ----
__device__ __forceinline__ float blo(unsigned u) { return __uint_as_float(u << 16); }
__device__ __forceinline__ float bhi(unsigned u) { return __uint_as_float(u & 0xFFFF0000u); }
__device__ __forceinline__ unsigned f2b(float x) {
  unsigned u = __float_as_uint(x);
  return (u + 0x7FFFu + ((u >> 16) & 1u)) >> 16;  // RNE
}
__device__ __forceinline__ unsigned pack2(float a, float b) {
  return f2b(a) | (f2b(b) << 16);
}

// ---- bucket histogram: bcnt[b] += #edges with dst>>9 == b ----
__global__ void k_bhist(const int* __restrict__ dst, int E, int* __restrict__ bcnt,
                        int NB) {
  __shared__ int h[256];
  int t = threadIdx.x;
  if (t < NB) h[t] = 0;
  __syncthreads();
  for (int i = blockIdx.x * 256 + t; i < E; i += gridDim.x * 256)
    atomicAdd(&h[dst[i] >> 9], 1);
  __syncthreads();
  if (t < NB && h[t]) atomicAdd(&bcnt[t], h[t]);
}

// ---- tiny scan over buckets (<=256), one block of 256 threads ----
__global__ void k_bscan(const int* __restrict__ bcnt, int* __restrict__ boff,
                        int* __restrict__ bcur, int NB, int E, int* __restrict__ row,
                        int N) {
  __shared__ int wsum[4];
  int t = threadIdx.x, lane = t & 63, w = t >> 6;
  int v = (t < NB) ? bcnt[t] : 0;
  int x = v;
#pragma unroll
  for (int off = 1; off < 64; off <<= 1) {
    int y = __shfl_up(x, off);
    if (lane >= off) x += y;
  }
  if (lane == 63) wsum[w] = x;
  __syncthreads();
  int woff = 0;
  for (int j = 0; j < w; ++j) woff += wsum[j];
  int ex = woff + x - v;
  if (t < NB) { boff[t] = ex; bcur[t] = ex; }
  if (t == 0) { boff[NB] = E; row[N] = E; }
}

// ---- blocked partition: per-block LDS hist -> one global reserve per bucket ->
//      LDS staging grouped by bucket -> coalesced windowed writes ----
__global__ __launch_bounds__(256) void k_bucket2(const int* __restrict__ src,
                                                 const int* __restrict__ dst, int E,
                                                 int* __restrict__ bcur,
                                                 int* __restrict__ bdata, int NB) {
  __shared__ int hist[256];
  __shared__ int lofs[256];
  __shared__ int delta[256];
  __shared__ int lcur[256];
  __shared__ int wsum[4];
  __shared__ int stage[CHUNK];
  int t = threadIdx.x;
  int base = blockIdx.x * CHUNK;
  int cnt = min(CHUNK, E - base);
  hist[t] = 0;
  __syncthreads();
  for (int i = t; i < cnt; i += 256) atomicAdd(&hist[dst[base + i] >> 9], 1);
  __syncthreads();
  int v = hist[t];
  int lane = t & 63, w = t >> 6;
  int x = v;
#pragma unroll
  for (int off = 1; off < 64; off <<= 1) {
    int y = __shfl_up(x, off);
    if (lane >= off) x += y;
  }
  if (lane == 63) wsum[w] = x;
  __syncthreads();
  int woff = 0;
  for (int j = 0; j < w; ++j) woff += wsum[j];
  int ex = woff + x - v;
  lofs[t] = ex;
  lcur[t] = ex;
  if (t < NB) delta[t] = atomicAdd(&bcur[t], v) - ex;  // global window base - local base
  __syncthreads();
  for (int i = t; i < cnt; i += 256) {
    int d = dst[base + i];
    int b = d >> 9;
    int p = atomicAdd(&lcur[b], 1);
    stage[p] = (src[base + i] << 9) | (d & 511);
  }
  __syncthreads();
  for (int i = t; i < cnt; i += 256) {
    int lo = 0, hi = NB;  // largest b with lofs[b] <= i
    while (hi - lo > 1) {
      int mid = (lo + hi) >> 1;
      if (lofs[mid] <= i) lo = mid; else hi = mid;
    }
    bdata[delta[lo] + i] = stage[i];
  }
}

// ---- per-bucket: local hist -> scan -> row/dinv/col ----
__global__ __launch_bounds__(256) void k_build(const int* __restrict__ bdata,
                                               const int* __restrict__ boff,
                                               int* __restrict__ col,
                                               int* __restrict__ row,
                                               float* __restrict__ dinv, int N) {
  __shared__ int hist[512];
  __shared__ int excl[512];
  __shared__ int wsum[4];
  int b = blockIdx.x, t = threadIdx.x;
  int s = boff[b], e = boff[b + 1];
  int n0 = b << 9;
  hist[t] = 0; hist[t + 256] = 0;
  __syncthreads();
  for (int i = s + t; i < e; i += 256) atomicAdd(&hist[bdata[i] & 511], 1);
  __syncthreads();
  int a0 = hist[2 * t], a1 = hist[2 * t + 1];
  int ps = a0 + a1;
  int lane = t & 63, w = t >> 6;
  int x = ps;
#pragma unroll
  for (int off = 1; off < 64; off <<= 1) {
    int y = __shfl_up(x, off);
    if (lane >= off) x += y;
  }
  if (lane == 63) wsum[w] = x;
  __syncthreads();
  int woff = 0;
  for (int j = 0; j < w; ++j) woff += wsum[j];
  int ex = woff + x - ps;
  excl[2 * t] = ex;
  excl[2 * t + 1] = ex + a0;
  __syncthreads();
  for (int l = t; l < 512; l += 256) {
    int n = n0 + l;
    if (n < N) {
      row[n] = s + excl[l];
      dinv[n] = rsqrtf((float)(hist[l] + 1));
    }
  }
  __syncthreads();
  for (int i = s + t; i < e; i += 256) {
    int v = bdata[i];
    int p = atomicAdd(&excl[v & 511], 1);
    col[s + p] = v >> 9;
  }
}

// C[M,64](bf16) = A[M,K] @ W[K,64](f32). A is f32 (ABF=0) or bf16 (ABF=1).
// 256 thr, 128x64 tile, 8x4 micro, fp32 accumulate, bf16 store.
template <int ABF>
__global__ __launch_bounds__(256) void k_gemm128(const void* __restrict__ Av,
                                                 const float* __restrict__ W,
                                                 unsigned short* __restrict__ C,
                                                 int M, int K) {
  __shared__ float as[32][132];
  __shared__ float bs[32][68];
  int tid = threadIdx.x;
  int tx = tid & 15;
  int ty = tid >> 4;
  int row0 = blockIdx.x * 128;
  float acc[8][4] = {};
  for (int k0 = 0; k0 < K; k0 += 32) {
    {
      int r = tid >> 1;
      int kk = (tid & 1) * 16;
      int grow = row0 + r;
      if (ABF) {
        uint4 u0 = make_uint4(0, 0, 0, 0), u1 = u0;
        if (grow < M) {
          const uint4* p =
              (const uint4*)((const unsigned short*)Av + (size_t)grow * K + k0 + kk);
          u0 = p[0]; u1 = p[1];
        }
        as[kk + 0][r] = blo(u0.x);  as[kk + 1][r] = bhi(u0.x);
        as[kk + 2][r] = blo(u0.y);  as[kk + 3][r] = bhi(u0.y);
        as[kk + 4][r] = blo(u0.z);  as[kk + 5][r] = bhi(u0.z);
        as[kk + 6][r] = blo(u0.w);  as[kk + 7][r] = bhi(u0.w);
        as[kk + 8][r] = blo(u1.x);  as[kk + 9][r] = bhi(u1.x);
        as[kk + 10][r] = blo(u1.y); as[kk + 11][r] = bhi(u1.y);
        as[kk + 12][r] = blo(u1.z); as[kk + 13][r] = bhi(u1.z);
        as[kk + 14][r] = blo(u1.w); as[kk + 15][r] = bhi(u1.w);
      } else {
        float4 v0 = make_float4(0.f, 0.f, 0.f, 0.f), v1 = v0, v2 = v0, v3 = v0;
        if (grow < M) {
          const float* srcp = (const float*)Av + (size_t)grow * K + k0 + kk;
          v0 = ((const float4*)srcp)[0];
          v1 = ((const float4*)srcp)[1];
          v2 = ((const float4*)srcp)[2];
          v3 = ((const float4*)srcp)[3];
        }
        as[kk + 0][r] = v0.x;  as[kk + 1][r] = v0.y;  as[kk + 2][r] = v0.z;  as[kk + 3][r] = v0.w;
        as[kk + 4][r] = v1.x;  as[kk + 5][r] = v1.y;  as[kk + 6][r] = v1.z;  as[kk + 7][r] = v1.w;
        as[kk + 8][r] = v2.x;  as[kk + 9][r] = v2.y;  as[kk + 10][r] = v2.z; as[kk + 11][r] = v2.w;
        as[kk + 12][r] = v3.x; as[kk + 13][r] = v3.y; as[kk + 14][r] = v3.z; as[kk + 15][r] = v3.w;
      }
    }
    {
      int kk = tid >> 3;
      int n = (tid & 7) * 8;
      const float* srcp = W + (size_t)(k0 + kk) * 64 + n;
      float4 v0 = *(const float4*)(srcp);
      float4 v1 = *(const float4*)(srcp + 4);
      *(float4*)&bs[kk][n] = v0;
      *(float4*)&bs[kk][n + 4] = v1;
    }
    __syncthreads();
#pragma unroll
    for (int kk = 0; kk < 32; ++kk) {
      float4 a0 = *(const float4*)&as[kk][ty * 8];
      float4 a1 = *(const float4*)&as[kk][ty * 8 + 4];
      float4 b = *(const float4*)&bs[kk][tx * 4];
      float av[8] = {a0.x, a0.y, a0.z, a0.w, a1.x, a1.y, a1.z, a1.w};
      float bv[4] = {b.x, b.y, b.z, b.w};
#pragma unroll
      for (int i = 0; i < 8; ++i)
#pragma unroll
        for (int j = 0; j < 4; ++j) acc[i][j] += av[i] * bv[j];
    }
    __syncthreads();
  }
  int r0 = row0 + ty * 8, c0 = tx * 4;
#pragma unroll
  for (int i = 0; i < 8; ++i) {
    int r = r0 + i;
    if (r < M) {
      uint2 o;
      o.x = pack2(acc[i][0], acc[i][1]);
      o.y = pack2(acc[i][2], acc[i][3]);
      *(uint2*)&C[(size_t)r * 64 + c0] = o;
    }
  }
}

// out[i,:] = bf16( dinv[i]*( sum_j dinv[j]*h[j,:] + dinv[i]*h[i,:] ) + bias )
// h rows are 64 bf16 = 128 B. 8 edge-groups of 8 lanes; each lane gathers a
// uint4 (8 bf16) -> 1024 B per vector instruction covering 8 neighbor rows.
__global__ __launch_bounds__(256) void k_agg(const unsigned short* __restrict__ h,
                                             const int* __restrict__ row,
                                             const int* __restrict__ col,
                                             const float* __restrict__ dinv,
                                             const float* __restrict__ bias,
                                             unsigned short* __restrict__ out, int N) {
  int w = threadIdx.x >> 6, lane = threadIdx.x & 63;
  int g = lane >> 3;  // edge-group 0..7
  int f = lane & 7;   // feature octet: features [8f, 8f+8)
  int i = blockIdx.x * 4 + w;
  if (i >= N) return;
  float di = dinv[i];
  int s = row[i], e = row[i + 1];
  float4 aA = make_float4(0.f, 0.f, 0.f, 0.f), aB = aA;
  if (g == 0) {  // self-loop term, counted once
    uint4 hv = ((const uint4*)(h + (size_t)i * 64))[f];
    aA.x = di * blo(hv.x); aA.y = di * bhi(hv.x);
    aA.z = di * blo(hv.y); aA.w = di * bhi(hv.y);
    aB.x = di * blo(hv.z); aB.y = di * bhi(hv.z);
    aB.z = di * blo(hv.w); aB.w = di * bhi(hv.w);
  }
  for (int base = s; base < e; base += 64) {
    int idx = base + lane;
    int cidx = (idx < e) ? col[idx] : 0;
    float dv = (idx < e) ? dinv[cidx] : 0.f;  // 0-weight padding for tail
    int cnt = min(64, e - base);
    int nt = (cnt + 7) >> 3;
    for (int t = 0; t < nt; ++t) {
      int sl = t * 8 + g;
      int j = __shfl(cidx, sl);
      float dj = __shfl(dv, sl);
      uint4 hv = ((const uint4*)(h + (size_t)j * 64))[f];
      aA.x += dj * blo(hv.x); aA.y += dj * bhi(hv.x);
      aA.z += dj * blo(hv.y); aA.w += dj * bhi(hv.y);
      aB.x += dj * blo(hv.z); aB.y += dj * bhi(hv.z);
      aB.z += dj * blo(hv.w); aB.w += dj * bhi(hv.w);
    }
  }
#pragma unroll
  for (int m = 8; m < 64; m <<= 1) {
    aA.x += __shfl_xor(aA.x, m); aA.y += __shfl_xor(aA.y, m);
    aA.z += __shfl_xor(aA.z, m); aA.w += __shfl_xor(aA.w, m);
    aB.x += __shfl_xor(aB.x, m); aB.y += __shfl_xor(aB.y, m);
    aB.z += __shfl_xor(aB.z, m); aB.w += __shfl_xor(aB.w, m);
  }
  if (lane < 8) {
    float4 b0 = *(const float4*)&bias[f * 8];
    float4 b1 = *(const float4*)&bias[f * 8 + 4];
    uint4 o;
    o.x = pack2(di * aA.x + b0.x, di * aA.y + b0.y);
    o.y = pack2(di * aA.z + b0.z, di * aA.w + b0.w);
    o.z = pack2(di * aB.x + b1.x, di * aB.y + b1.y);
    o.w = pack2(di * aB.z + b1.z, di * aB.w + b1.w);
    ((uint4*)(out + (size_t)i * 64))[f] = o;
  }
}

// fold: M = Wproj[sel]@Wl1 (64x64); W2m = W2@M; c2 = b2@M; cvec = bproj@Wl1 + bl1
__global__ __launch_bounds__(1024) void k_fold2(
    const float* __restrict__ Wproj, const float* __restrict__ bproj,
    const float* __restrict__ Wl1, const float* __restrict__ bl1,
    const float* __restrict__ Wp2, const float* __restrict__ bp2,
    const float* __restrict__ Ws2, const float* __restrict__ bs2,
    float* __restrict__ W2m_p, float* __restrict__ c2_p, float* __restrict__ W2m_s,
    float* __restrict__ c2_s, float* __restrict__ cvec) {
  int which = blockIdx.x;
  const float* W2 = which ? Ws2 : Wp2;
  const float* b2v = which ? bs2 : bp2;
  float* W2m = which ? W2m_s : W2m_p;
  float* c2 = which ? c2_s : c2_p;
  __shared__ float M[64][64];
  int t = threadIdx.x;
  for (int idx = t; idx < 4096; idx += 1024) {
    int a = idx >> 6, c = idx & 63;
    const float* wr = Wproj + (size_t)(which * 64 + a) * 128;
    float sum = 0.f;
    for (int k = 0; k < 128; ++k) sum += wr[k] * Wl1[(size_t)k * 64 + c];
    M[a][c] = sum;
  }
  __syncthreads();
  for (int idx = t; idx < 4096; idx += 1024) {
    int a = idx >> 6, c = idx & 63;
    float sum = 0.f;
    for (int k = 0; k < 64; ++k) sum += W2[a * 64 + k] * M[k][c];
    W2m[idx] = sum;
  }
  if (t < 64) {
    float sum = 0.f;
    for (int k = 0; k < 64; ++k) sum += b2v[k] * M[k][t];
    c2[t] = sum;
  }
  if (which == 0 && t >= 64 && t < 128) {
    int c = t - 64;
    float sum = bl1[c];
    for (int k = 0; k < 128; ++k) sum += bproj[k] * Wl1[(size_t)k * 64 + c];
    cvec[c] = sum;
  }
}

// out[e] = relu(P[ep[e],:] + S[es[e],:] + c) . wl2 + bl2   (8 lanes per edge,
// bf16 rows: one uint4 per lane = full 128-B row per 8-lane group)
__global__ void k_link(const unsigned short* __restrict__ P,
                       const unsigned short* __restrict__ S,
                       const int* __restrict__ ep, const int* __restrict__ es,
                       const float* __restrict__ cvec, const float* __restrict__ wl2,
                       const float* __restrict__ bl2, float* __restrict__ out, int EL) {
  int lane = threadIdx.x & 63;
  int g = lane >> 3;
  int f = lane & 7;
  int wave = threadIdx.x >> 6;
  float4 c0 = *(const float4*)&cvec[f * 8];
  float4 c1 = *(const float4*)&cvec[f * 8 + 4];
  float4 w0 = *(const float4*)&wl2[f * 8];
  float4 w1 = *(const float4*)&wl2[f * 8 + 4];
  float b2 = bl2[0];
  int e0 = blockIdx.x * 32 + wave * 8 + g;
  int step = gridDim.x * 32;
  for (int e = e0; e < EL; e += step) {
    int rp = ep[e], rs = es[e];
    uint4 pv = ((const uint4*)(P + (size_t)rp * 64))[f];
    uint4 sv = ((const uint4*)(S + (size_t)rs * 64))[f];
    float u, acc;
    u = blo(pv.x) + blo(sv.x) + c0.x; acc  = fmaxf(u, 0.f) * w0.x;
    u = bhi(pv.x) + bhi(sv.x) + c0.y; acc += fmaxf(u, 0.f) * w0.y;
    u = blo(pv.y) + blo(sv.y) + c0.z; acc += fmaxf(u, 0.f) * w0.z;
    u = bhi(pv.y) + bhi(sv.y) + c0.w; acc += fmaxf(u, 0.f) * w0.w;
    u = blo(pv.z) + blo(sv.z) + c1.x; acc += fmaxf(u, 0.f) * w1.x;
    u = bhi(pv.z) + bhi(sv.z) + c1.y; acc += fmaxf(u, 0.f) * w1.y;
    u = blo(pv.w) + blo(sv.w) + c1.z; acc += fmaxf(u, 0.f) * w1.z;
    u = bhi(pv.w) + bhi(sv.w) + c1.w; acc += fmaxf(u, 0.f) * w1.w;
    acc += __shfl_xor(acc, 1);
    acc += __shfl_xor(acc, 2);
    acc += __shfl_xor(acc, 4);
    if (f == 0) out[e] = acc + b2;
  }
}

extern "C" void kernel_launch(void* const* d_in, const int* in_sizes, int n_in,
                              void* d_out, int out_size, void* d_ws, size_t ws_size,
                              hipStream_t stream) {
  const float* x_p  = (const float*)d_in[0];
  const float* x_s  = (const float*)d_in[1];
  const int*   ei_p = (const int*)d_in[2];
  const int*   ei_s = (const int*)d_in[3];
  const int*   ed_p = (const int*)d_in[4];
  const int*   ed_s = (const int*)d_in[5];
  const float* Wp1 = (const float*)d_in[6];  const float* bp1 = (const float*)d_in[7];
  const float* Ws1 = (const float*)d_in[8];  const float* bs1 = (const float*)d_in[9];
  const float* Wp2 = (const float*)d_in[10]; const float* bp2 = (const float*)d_in[11];
  const float* Ws2 = (const float*)d_in[12]; const float* bs2 = (const float*)d_in[13];
  const float* Wproj = (const float*)d_in[14]; const float* bproj = (const float*)d_in[15];
  const float* Wl1 = (const float*)d_in[16]; const float* bl1 = (const float*)d_in[17];
  const float* Wl2 = (const float*)d_in[18]; const float* bl2 = (const float*)d_in[19];
  float* out = (float*)d_out;

  char* wsp = (char*)d_ws;
  size_t off = 0;
  auto alloc = [&](size_t b) -> void* {
    void* p = wsp + off;
    off = (off + b + 255) & ~(size_t)255;
    return p;
  };
  // bf16 feature buffers: N x 64 x 2 B
  unsigned short* bufA_p = (unsigned short*)alloc((size_t)NPn * 64 * 2);
  unsigned short* bufB_p = (unsigned short*)alloc((size_t)NPn * 64 * 2);
  unsigned short* bufA_s = (unsigned short*)alloc((size_t)NSn * 64 * 2);
  unsigned short* bufB_s = (unsigned short*)alloc((size_t)NSn * 64 * 2);
  int*   col_p  = (int*)alloc((size_t)EPe * 4);
  int*   col_s  = (int*)alloc((size_t)ESe * 4);
  float* dinv_p = (float*)alloc((size_t)NPn * 4);
  float* dinv_s = (float*)alloc((size_t)NSn * 4);
  int*   row_p  = (int*)alloc((size_t)(NPn + 1) * 4);
  int*   row_s  = (int*)alloc((size_t)(NSn + 1) * 4);
  int*   bcnt_p = (int*)alloc(256 * 4);
  int*   bcnt_s = (int*)alloc(256 * 4);
  int*   boff_p = (int*)alloc(257 * 4);
  int*   boff_s = (int*)alloc(257 * 4);
  int*   bcur_p = (int*)alloc(256 * 4);
  int*   bcur_s = (int*)alloc(256 * 4);
  float* W2m_p  = (float*)alloc(64 * 64 * 4);
  float* W2m_s  = (float*)alloc(64 * 64 * 4);
  float* c2_p   = (float*)alloc(64 * 4);
  float* c2_s   = (float*)alloc(64 * 4);
  float* cvec   = (float*)alloc(64 * 4);
  // bdata needs its own space now (bf16 bufA is exactly E*4 bytes but keep clean):
  int* bdata_p = (int*)alloc((size_t)EPe * 4);
  int* bdata_s = (int*)alloc((size_t)ESe * 4);
  (void)ws_size; (void)n_in; (void)in_sizes; (void)out_size;

  const int* src_p = ei_p;           const int* dst_p = ei_p + EPe;
  const int* src_s = ei_s;           const int* dst_s = ei_s + ESe;

  hipMemsetAsync(bcnt_p, 0, 256 * 4, stream);
  hipMemsetAsync(bcnt_s, 0, 256 * 4, stream);

  // weight folding (independent)
  k_fold2<<<2, 1024, 0, stream>>>(Wproj, bproj, Wl1, bl1, Wp2, bp2, Ws2, bs2,
                                  W2m_p, c2_p, W2m_s, c2_s, cvec);

  // bucket counting-sort CSR build
  k_bhist<<<1280, 256, 0, stream>>>(dst_p, EPe, bcnt_p, NB_P);
  k_bhist<<<1280, 256, 0, stream>>>(dst_s, ESe, bcnt_s, NB_S);
  k_bscan<<<1, 256, 0, stream>>>(bcnt_p, boff_p, bcur_p, NB_P, EPe, row_p, NPn);
  k_bscan<<<1, 256, 0, stream>>>(bcnt_s, boff_s, bcur_s, NB_S, ESe, row_s, NSn);
  k_bucket2<<<(EPe + CHUNK - 1) / CHUNK, 256, 0, stream>>>(src_p, dst_p, EPe, bcur_p,
                                                           bdata_p, NB_P);
  k_bucket2<<<(ESe + CHUNK - 1) / CHUNK, 256, 0, stream>>>(src_s, dst_s, ESe, bcur_s,
                                                           bdata_s, NB_S);
  k_build<<<NB_P, 256, 0, stream>>>(bdata_p, boff_p, col_p, row_p, dinv_p, NPn);
  k_build<<<NB_S, 256, 0, stream>>>(bdata_s, boff_s, col_s, row_s, dinv_s, NSn);

  // protein: t = x@W1 ; h1 = Agg(t)+b1 ; t = h1@W2m ; P = Agg(t)+c2
  k_gemm128<0><<<(NPn + 127) / 128, 256, 0, stream>>>(x_p, Wp1, bufA_p, NPn, PDk);
  k_agg<<<(NPn + 3) / 4, 256, 0, stream>>>(bufA_p, row_p, col_p, dinv_p, bp1, bufB_p, NPn);
  k_gemm128<1><<<(NPn + 127) / 128, 256, 0, stream>>>(bufB_p, W2m_p, bufA_p, NPn, 64);
  k_agg<<<(NPn + 3) / 4, 256, 0, stream>>>(bufA_p, row_p, col_p, dinv_p, c2_p, bufB_p, NPn);

  // substrate
  k_gemm128<0><<<(NSn + 127) / 128, 256, 0, stream>>>(x_s, Ws1, bufA_s, NSn, SDk);
  k_agg<<<(NSn + 3) / 4, 256, 0, stream>>>(bufA_s, row_s, col_s, dinv_s, bs1, bufB_s, NSn);
  k_gemm128<1><<<(NSn + 127) / 128, 256, 0, stream>>>(bufB_s, W2m_s, bufA_s, NSn, 64);
  k_agg<<<(NSn + 3) / 4, 256, 0, stream>>>(bufA_s, row_s, col_s, dinv_s, c2_s, bufB_s, NSn);

  // link predictor
  k_link<<<(ELe + 31) / 32, 256, 0, stream>>>(bufB_p, bufB_s, ed_p, ed_s, cvec, Wl2,
                                              bl2, out, ELe);
}